// Round 1
// baseline (5107.913 us; speedup 1.0000x reference)
//
#include <hip/hip_runtime.h>
#include <hip/hip_bf16.h>

// GCN encoder: 2x GCNConv(relu) + global mean pool.
// N=100000 nodes, E=1.6M edges, D 128->128->64, G=64 graphs.
// Round 1: correctness-first fp32 implementation, atomic scatter-add.

#define DIN 128
#define DH  128
#define DOUTC 64

// ---------------- small utility kernels ----------------

__global__ void fill1_kernel(float* __restrict__ p, int n) {
    int i = blockIdx.x * blockDim.x + threadIdx.x;
    if (i < n) p[i] = 1.0f;
}

__global__ void zero_kernel(float* __restrict__ p, int n) {
    int i = blockIdx.x * blockDim.x + threadIdx.x;
    if (i < n) p[i] = 0.0f;
}

__global__ void deg_count_kernel(float* __restrict__ deg, const int* __restrict__ dst, int e) {
    int i = blockIdx.x * blockDim.x + threadIdx.x;
    if (i < e) unsafeAtomicAdd(&deg[dst[i]], 1.0f);
}

__global__ void finish_dinv_kernel(float* __restrict__ d, int n) {
    int i = blockIdx.x * blockDim.x + threadIdx.x;
    if (i < n) d[i] = rsqrtf(d[i]);   // deg >= 1 always (self-loop)
}

__global__ void edge_norm_kernel(float* __restrict__ norm, const float* __restrict__ dinv,
                                 const int* __restrict__ src, const int* __restrict__ dst, int e) {
    int i = blockIdx.x * blockDim.x + threadIdx.x;
    if (i < e) norm[i] = dinv[src[i]] * dinv[dst[i]];
}

// ---------------- GEMM: Y[n][DOUT] = X[n][128] * W[128][DOUT] ----------------
// 256 threads/block, 64-row tile staged in LDS, W streamed (L2-hot, only 32/64KB).
template <int DOUT>
__global__ __launch_bounds__(256) void gemm_k128(const float* __restrict__ X,
                                                 const float* __restrict__ W,
                                                 float* __restrict__ Y, int n) {
    constexpr int K = 128;
    constexpr int TR = 64;               // tile rows
    constexpr int COLV = DOUT / 4;       // float4 col groups (32 or 16)
    constexpr int RS = 256 / COLV;       // row slots (8 or 16)
    constexpr int RPT = TR / RS;         // rows per thread (8 or 4)

    __shared__ float xs[TR][K];          // 32 KB

    const int tid = threadIdx.x;
    const int row0 = blockIdx.x * TR;

    // stage X tile: 2048 float4, 8 per thread, coalesced
    #pragma unroll
    for (int i = 0; i < 8; ++i) {
        int idx = i * 256 + tid;         // float4 index in tile
        int r = idx >> 5;                // 32 float4 per row
        int c = idx & 31;
        int gr = row0 + r;
        float4 v = make_float4(0.f, 0.f, 0.f, 0.f);
        if (gr < n) v = reinterpret_cast<const float4*>(X)[(size_t)gr * 32 + c];
        reinterpret_cast<float4*>(&xs[0][0])[idx] = v;
    }
    __syncthreads();

    const int col = tid % COLV;
    const int rslot = tid / COLV;

    float4 acc[RPT];
    #pragma unroll
    for (int r = 0; r < RPT; ++r) acc[r] = make_float4(0.f, 0.f, 0.f, 0.f);

    #pragma unroll 4
    for (int k = 0; k < K; ++k) {
        float4 w = reinterpret_cast<const float4*>(W)[k * COLV + col];
        #pragma unroll
        for (int r = 0; r < RPT; ++r) {
            float xv = xs[rslot + r * RS][k];
            acc[r].x += xv * w.x;
            acc[r].y += xv * w.y;
            acc[r].z += xv * w.z;
            acc[r].w += xv * w.w;
        }
    }

    #pragma unroll
    for (int r = 0; r < RPT; ++r) {
        int gr = row0 + rslot + r * RS;
        if (gr < n) reinterpret_cast<float4*>(Y)[(size_t)gr * COLV + col] = acc[r];
    }
}

// ---------------- aggregation ----------------

// AGG[i][:] = XW[i][:] * dinv[i]^2   (self-loop contribution, also inits buffer)
template <int D>
__global__ void selfloop_init_kernel(const float* __restrict__ XW, const float* __restrict__ dinv,
                                     float* __restrict__ AGG, int n) {
    constexpr int Q = D / 4;
    int t = blockIdx.x * blockDim.x + threadIdx.x;
    if (t >= n * Q) return;
    int i = t / Q;
    float f = dinv[i];
    float s = f * f;
    float4 v = reinterpret_cast<const float4*>(XW)[t];
    float4 o = make_float4(v.x * s, v.y * s, v.z * s, v.w * s);
    reinterpret_cast<float4*>(AGG)[t] = o;
}

// AGG[dst] += XW[src] * norm  — one float4 per thread, D/4 threads per edge
template <int D>
__global__ void edge_agg_kernel(const float* __restrict__ XW, float* __restrict__ AGG,
                                const int* __restrict__ src, const int* __restrict__ dst,
                                const float* __restrict__ norm, int e_total) {
    constexpr int Q = D / 4;
    long long t = (long long)blockIdx.x * blockDim.x + threadIdx.x;
    int e = (int)(t / Q);
    int c = (int)(t % Q);
    if (e >= e_total) return;
    int s = src[e];
    int d = dst[e];
    float nv = norm[e];
    float4 v = reinterpret_cast<const float4*>(XW)[(size_t)s * Q + c];
    float* a = AGG + (size_t)d * D + (size_t)c * 4;
    unsafeAtomicAdd(a + 0, v.x * nv);
    unsafeAtomicAdd(a + 1, v.y * nv);
    unsafeAtomicAdd(a + 2, v.z * nv);
    unsafeAtomicAdd(a + 3, v.w * nv);
}

// H = relu(AGG + b) in place
template <int D>
__global__ void bias_relu_kernel(float* __restrict__ AGG, const float* __restrict__ b, int n) {
    constexpr int Q = D / 4;
    int t = blockIdx.x * blockDim.x + threadIdx.x;
    if (t >= n * Q) return;
    int c = t % Q;
    float4 bv = reinterpret_cast<const float4*>(b)[c];
    float4 v = reinterpret_cast<float4*>(AGG)[t];
    v.x = fmaxf(v.x + bv.x, 0.f);
    v.y = fmaxf(v.y + bv.y, 0.f);
    v.z = fmaxf(v.z + bv.z, 0.f);
    v.w = fmaxf(v.w + bv.w, 0.f);
    reinterpret_cast<float4*>(AGG)[t] = v;
}

// ---------------- pooling ----------------

__global__ void pool_sum_kernel(const float* __restrict__ H, const int* __restrict__ batch,
                                float* __restrict__ sums, float* __restrict__ cnt, int n) {
    int t = blockIdx.x * blockDim.x + threadIdx.x;
    if (t >= n * DOUTC) return;
    int i = t >> 6;
    int j = t & 63;
    int g = batch[i];
    unsafeAtomicAdd(&sums[g * DOUTC + j], H[(size_t)i * DOUTC + j]);
    if (j == 0) unsafeAtomicAdd(&cnt[g], 1.0f);
}

__global__ void pool_finish_kernel(const float* __restrict__ sums, const float* __restrict__ cnt,
                                   float* __restrict__ out, int g_total) {
    int t = blockIdx.x * blockDim.x + threadIdx.x;
    if (t >= g_total * DOUTC) return;
    int g = t >> 6;
    out[t] = sums[t] / fmaxf(cnt[g], 1.0f);
}

// ---------------- launch ----------------

extern "C" void kernel_launch(void* const* d_in, const int* in_sizes, int n_in,
                              void* d_out, int out_size, void* d_ws, size_t ws_size,
                              hipStream_t stream) {
    const float* x    = (const float*)d_in[0];
    const int*   ei   = (const int*)d_in[1];   // [2][E], int32 per harness convention
    const int*   batch= (const int*)d_in[2];
    const float* W1   = (const float*)d_in[3];
    const float* b1   = (const float*)d_in[4];
    const float* W2   = (const float*)d_in[5];
    const float* b2   = (const float*)d_in[6];
    float* out = (float*)d_out;

    const int N = in_sizes[0] / DIN;
    const int E = in_sizes[1] / 2;
    const int G = out_size / DOUTC;

    const int* esrc = ei;
    const int* edst = ei + E;

    // workspace carve-out (256B aligned)
    char* ws = (char*)d_ws;
    size_t off = 0;
    auto alloc = [&](size_t bytes) -> void* {
        void* p = ws + off;
        off = (off + bytes + 255) & ~(size_t)255;
        return p;
    };
    float* dinv = (float*)alloc((size_t)N * 4);
    float* norm = (float*)alloc((size_t)E * 4);
    float* bufA = (float*)alloc((size_t)N * DH * 4);   // xw1, later hw2
    float* bufB = (float*)alloc((size_t)N * DH * 4);   // agg1/h1, later agg2/h2
    float* sums = (float*)alloc((size_t)G * DOUTC * 4 + (size_t)G * 4);
    float* cnt  = sums + G * DOUTC;

    const int B = 256;
    auto cdiv = [](long long a, long long b) { return (int)((a + b - 1) / b); };

    // degrees & edge norms
    fill1_kernel<<<cdiv(N, B), B, 0, stream>>>(dinv, N);
    zero_kernel<<<cdiv(G * DOUTC + G, B), B, 0, stream>>>(sums, G * DOUTC + G);
    deg_count_kernel<<<cdiv(E, B), B, 0, stream>>>(dinv, edst, E);
    finish_dinv_kernel<<<cdiv(N, B), B, 0, stream>>>(dinv, N);
    edge_norm_kernel<<<cdiv(E, B), B, 0, stream>>>(norm, dinv, esrc, edst, E);

    // ---- layer 1 ----
    gemm_k128<DH><<<cdiv(N, 64), B, 0, stream>>>(x, W1, bufA, N);
    selfloop_init_kernel<DH><<<cdiv((long long)N * (DH / 4), B), B, 0, stream>>>(bufA, dinv, bufB, N);
    edge_agg_kernel<DH><<<cdiv((long long)E * (DH / 4), B), B, 0, stream>>>(bufA, bufB, esrc, edst, norm, E);
    bias_relu_kernel<DH><<<cdiv((long long)N * (DH / 4), B), B, 0, stream>>>(bufB, b1, N);

    // ---- layer 2 ----
    gemm_k128<DOUTC><<<cdiv(N, 64), B, 0, stream>>>(bufB, W2, bufA, N);
    selfloop_init_kernel<DOUTC><<<cdiv((long long)N * (DOUTC / 4), B), B, 0, stream>>>(bufA, dinv, bufB, N);
    edge_agg_kernel<DOUTC><<<cdiv((long long)E * (DOUTC / 4), B), B, 0, stream>>>(bufA, bufB, esrc, edst, norm, E);
    bias_relu_kernel<DOUTC><<<cdiv((long long)N * (DOUTC / 4), B), B, 0, stream>>>(bufB, b2, N);

    // ---- pool ----
    pool_sum_kernel<<<cdiv((long long)N * DOUTC, B), B, 0, stream>>>(bufB, batch, sums, cnt, N);
    pool_finish_kernel<<<cdiv(G * DOUTC, B), B, 0, stream>>>(sums, cnt, out, G);
}

// Round 2
// 1372.520 us; speedup vs baseline: 3.7216x; 3.7216x over previous
//
#include <hip/hip_runtime.h>
#include <hip/hip_bf16.h>

// GCN encoder: 2x GCNConv(relu) + global mean pool.
// N=100000 nodes, E=1.6M edges, D 128->128->64, G=64 graphs.
// Round 2: CSR-by-dst aggregation (no float atomics), fused selfloop+bias+relu.

#define DIN 128
#define DH  128
#define DOUTC 64

// ---------------- small utility kernels ----------------

__global__ void zero_i32_kernel(int* __restrict__ p, int n) {
    int i = blockIdx.x * blockDim.x + threadIdx.x;
    if (i < n) p[i] = 0;
}

__global__ void zero_f32_kernel(float* __restrict__ p, int n) {
    int i = blockIdx.x * blockDim.x + threadIdx.x;
    if (i < n) p[i] = 0.0f;
}

__global__ void deg_count_kernel(int* __restrict__ cnt, const int* __restrict__ dst, int e) {
    int i = blockIdx.x * blockDim.x + threadIdx.x;
    if (i < e) atomicAdd(&cnt[dst[i]], 1);
}

// dinv[i] = rsqrt(in_degree + 1)   (self-loop included)
__global__ void dinv_kernel(float* __restrict__ dinv, const int* __restrict__ cnt, int n) {
    int i = blockIdx.x * blockDim.x + threadIdx.x;
    if (i < n) dinv[i] = rsqrtf((float)(cnt[i] + 1));
}

// ---------------- prefix scan (exclusive) over deg -> row_ptr ----------------
// scan1: per-block (1024 elems) exclusive positions + block sums
__global__ __launch_bounds__(256) void scan1_kernel(const int* __restrict__ deg,
                                                    int* __restrict__ excl,
                                                    int* __restrict__ blockSums, int n) {
    __shared__ int sh[256];
    const int tid = threadIdx.x;
    const int base = blockIdx.x * 1024 + tid * 4;
    int v[4];
    #pragma unroll
    for (int j = 0; j < 4; ++j) v[j] = (base + j < n) ? deg[base + j] : 0;
    int tsum = v[0] + v[1] + v[2] + v[3];
    sh[tid] = tsum;
    __syncthreads();
    // Hillis-Steele inclusive scan
    for (int off = 1; off < 256; off <<= 1) {
        int add = (tid >= off) ? sh[tid - off] : 0;
        __syncthreads();
        sh[tid] += add;
        __syncthreads();
    }
    int texcl = sh[tid] - tsum;
    int run = texcl;
    #pragma unroll
    for (int j = 0; j < 4; ++j) {
        if (base + j < n) excl[base + j] = run;
        run += v[j];
    }
    if (tid == 255) blockSums[blockIdx.x] = sh[255];
}

// scan2: sequential exclusive scan of block sums (<=128 entries)
__global__ void scan2_kernel(int* __restrict__ blockSums, int nb) {
    if (blockIdx.x == 0 && threadIdx.x == 0) {
        int run = 0;
        for (int i = 0; i < nb; ++i) {
            int t = blockSums[i];
            blockSums[i] = run;
            run += t;
        }
    }
}

// scan3: add block offsets; set row_ptr[n] = E
__global__ void scan3_kernel(int* __restrict__ row_ptr, const int* __restrict__ blockSums,
                             int n, int e_total) {
    int i = blockIdx.x * blockDim.x + threadIdx.x;
    if (i < n) row_ptr[i] += blockSums[i >> 10];
    if (i == 0) row_ptr[n] = e_total;
}

// scatter edges into CSR: epack[pos] = {src, dinv[src]*dinv[dst]}
__global__ void scatter_kernel(const int* __restrict__ src, const int* __restrict__ dst,
                               const float* __restrict__ dinv, const int* __restrict__ row_ptr,
                               int* __restrict__ cursor, int2* __restrict__ ep, int e_total) {
    int e = blockIdx.x * blockDim.x + threadIdx.x;
    if (e >= e_total) return;
    int s = src[e];
    int d = dst[e];
    int pos = row_ptr[d] + atomicAdd(&cursor[d], 1);
    ep[pos] = make_int2(s, __float_as_int(dinv[s] * dinv[d]));
}

// ---------------- GEMM: Y[n][DOUT] = X[n][128] * W[128][DOUT] ----------------
template <int DOUT>
__global__ __launch_bounds__(256) void gemm_k128(const float* __restrict__ X,
                                                 const float* __restrict__ W,
                                                 float* __restrict__ Y, int n) {
    constexpr int K = 128;
    constexpr int TR = 64;               // tile rows
    constexpr int COLV = DOUT / 4;       // float4 col groups (32 or 16)
    constexpr int RS = 256 / COLV;       // row slots (8 or 16)
    constexpr int RPT = TR / RS;         // rows per thread (8 or 4)

    __shared__ float xs[TR][K];          // 32 KB

    const int tid = threadIdx.x;
    const int row0 = blockIdx.x * TR;

    #pragma unroll
    for (int i = 0; i < 8; ++i) {
        int idx = i * 256 + tid;
        int r = idx >> 5;
        int c = idx & 31;
        int gr = row0 + r;
        float4 v = make_float4(0.f, 0.f, 0.f, 0.f);
        if (gr < n) v = reinterpret_cast<const float4*>(X)[(size_t)gr * 32 + c];
        reinterpret_cast<float4*>(&xs[0][0])[idx] = v;
    }
    __syncthreads();

    const int col = tid % COLV;
    const int rslot = tid / COLV;

    float4 acc[RPT];
    #pragma unroll
    for (int r = 0; r < RPT; ++r) acc[r] = make_float4(0.f, 0.f, 0.f, 0.f);

    #pragma unroll 4
    for (int k = 0; k < K; ++k) {
        float4 w = reinterpret_cast<const float4*>(W)[k * COLV + col];
        #pragma unroll
        for (int r = 0; r < RPT; ++r) {
            float xv = xs[rslot + r * RS][k];
            acc[r].x += xv * w.x;
            acc[r].y += xv * w.y;
            acc[r].z += xv * w.z;
            acc[r].w += xv * w.w;
        }
    }

    #pragma unroll
    for (int r = 0; r < RPT; ++r) {
        int gr = row0 + rslot + r * RS;
        if (gr < n) reinterpret_cast<float4*>(Y)[(size_t)gr * COLV + col] = acc[r];
    }
}

// ---------------- fused CSR aggregation + selfloop + bias + relu ----------------
// One wave (64 lanes) per node. D=128: float2/lane; D=64: float/lane.
// OUT[i] = relu( sum_{e in CSR(i)} XW[src_e]*w_e  +  XW[i]*dinv[i]^2  +  bias )
template <int D>
__global__ __launch_bounds__(256) void agg_relu_kernel(const float* __restrict__ XW,
                                                       const int2* __restrict__ ep,
                                                       const int* __restrict__ row_ptr,
                                                       const float* __restrict__ dinv,
                                                       const float* __restrict__ bias,
                                                       float* __restrict__ OUT, int n) {
    const int tid = threadIdx.x;
    const int node = (blockIdx.x * 256 + tid) >> 6;
    const int lane = tid & 63;
    if (node >= n) return;

    const int start = row_ptr[node];
    const int end = row_ptr[node + 1];

    if constexpr (D == 128) {
        const float2* XW2 = reinterpret_cast<const float2*>(XW);
        float di = dinv[node];
        float sl = di * di;
        float2 v = XW2[(size_t)node * 64 + lane];
        float ax = v.x * sl, ay = v.y * sl;
        for (int p = start; p < end; ++p) {
            int2 m = ep[p];
            float w = __int_as_float(m.y);
            float2 u = XW2[(size_t)m.x * 64 + lane];
            ax += u.x * w;
            ay += u.y * w;
        }
        float2 b = reinterpret_cast<const float2*>(bias)[lane];
        float2 o;
        o.x = fmaxf(ax + b.x, 0.f);
        o.y = fmaxf(ay + b.y, 0.f);
        reinterpret_cast<float2*>(OUT)[(size_t)node * 64 + lane] = o;
    } else {
        float di = dinv[node];
        float sl = di * di;
        float acc = XW[(size_t)node * D + lane] * sl;
        for (int p = start; p < end; ++p) {
            int2 m = ep[p];
            float w = __int_as_float(m.y);
            acc += XW[(size_t)m.x * D + lane] * w;
        }
        float o = fmaxf(acc + bias[lane], 0.f);
        OUT[(size_t)node * D + lane] = o;
    }
}

// ---------------- pooling ----------------

__global__ void pool_sum_kernel(const float* __restrict__ H, const int* __restrict__ batch,
                                float* __restrict__ sums, float* __restrict__ cnt, int n) {
    int t = blockIdx.x * blockDim.x + threadIdx.x;
    if (t >= n * DOUTC) return;
    int i = t >> 6;
    int j = t & 63;
    int g = batch[i];
    unsafeAtomicAdd(&sums[g * DOUTC + j], H[(size_t)i * DOUTC + j]);
    if (j == 0) unsafeAtomicAdd(&cnt[g], 1.0f);
}

__global__ void pool_finish_kernel(const float* __restrict__ sums, const float* __restrict__ cnt,
                                   float* __restrict__ out, int g_total) {
    int t = blockIdx.x * blockDim.x + threadIdx.x;
    if (t >= g_total * DOUTC) return;
    int g = t >> 6;
    out[t] = sums[t] / fmaxf(cnt[g], 1.0f);
}

// ---------------- launch ----------------

extern "C" void kernel_launch(void* const* d_in, const int* in_sizes, int n_in,
                              void* d_out, int out_size, void* d_ws, size_t ws_size,
                              hipStream_t stream) {
    const float* x    = (const float*)d_in[0];
    const int*   ei   = (const int*)d_in[1];   // [2][E]
    const int*   batch= (const int*)d_in[2];
    const float* W1   = (const float*)d_in[3];
    const float* b1   = (const float*)d_in[4];
    const float* W2   = (const float*)d_in[5];
    const float* b2   = (const float*)d_in[6];
    float* out = (float*)d_out;

    const int N = in_sizes[0] / DIN;
    const int E = in_sizes[1] / 2;
    const int G = out_size / DOUTC;

    const int* esrc = ei;
    const int* edst = ei + E;

    // workspace carve-out (256B aligned)
    char* ws = (char*)d_ws;
    size_t off = 0;
    auto alloc = [&](size_t bytes) -> void* {
        void* p = ws + off;
        off = (off + bytes + 255) & ~(size_t)255;
        return p;
    };
    float* dinv    = (float*)alloc((size_t)N * 4);
    int*   row_ptr = (int*)alloc((size_t)(N + 1) * 4);
    int*   cursor  = (int*)alloc((size_t)N * 4);
    int*   blockSums = (int*)alloc(1024 * 4);
    int2*  epack   = (int2*)alloc((size_t)E * 8);
    float* bufA    = (float*)alloc((size_t)N * DH * 4);   // xw1, later hw2
    float* bufB    = (float*)alloc((size_t)N * DH * 4);   // h1, later h2
    float* sums    = (float*)alloc((size_t)G * DOUTC * 4 + (size_t)G * 4);
    float* cnt     = sums + G * DOUTC;

    const int B = 256;
    auto cdiv = [](long long a, long long b) { return (int)((a + b - 1) / b); };
    const int nScanBlocks = cdiv(N, 1024);

    // ---- CSR build ----
    zero_i32_kernel<<<cdiv(N, B), B, 0, stream>>>(cursor, N);
    zero_f32_kernel<<<cdiv(G * DOUTC + G, B), B, 0, stream>>>(sums, G * DOUTC + G);
    deg_count_kernel<<<cdiv(E, B), B, 0, stream>>>(cursor, edst, E);
    dinv_kernel<<<cdiv(N, B), B, 0, stream>>>(dinv, cursor, N);
    scan1_kernel<<<nScanBlocks, B, 0, stream>>>(cursor, row_ptr, blockSums, N);
    scan2_kernel<<<1, 64, 0, stream>>>(blockSums, nScanBlocks);
    scan3_kernel<<<cdiv(N, B), B, 0, stream>>>(row_ptr, blockSums, N, E);
    zero_i32_kernel<<<cdiv(N, B), B, 0, stream>>>(cursor, N);
    scatter_kernel<<<cdiv(E, B), B, 0, stream>>>(esrc, edst, dinv, row_ptr, cursor, epack, E);

    // ---- layer 1: h1 = relu(agg(x@W1) + b1) ----
    gemm_k128<DH><<<cdiv(N, 64), B, 0, stream>>>(x, W1, bufA, N);
    agg_relu_kernel<DH><<<cdiv(N, 4), B, 0, stream>>>(bufA, epack, row_ptr, dinv, b1, bufB, N);

    // ---- layer 2: h2 = relu(agg(h1@W2) + b2) ----
    gemm_k128<DOUTC><<<cdiv(N, 64), B, 0, stream>>>(bufB, W2, bufA, N);
    agg_relu_kernel<DOUTC><<<cdiv(N, 4), B, 0, stream>>>(bufA, epack, row_ptr, dinv, b2, bufB, N);

    // ---- pool ----
    pool_sum_kernel<<<cdiv((long long)N * DOUTC, B), B, 0, stream>>>(bufB, batch, sums, cnt, N);
    pool_finish_kernel<<<cdiv(G * DOUTC, B), B, 0, stream>>>(sums, cnt, out, G);
}

// Round 4
// 604.530 us; speedup vs baseline: 8.4494x; 2.2704x over previous
//
#include <hip/hip_runtime.h>
#include <hip/hip_bf16.h>

// GCN encoder: 2x GCNConv(relu) + global mean pool.
// N=100000 nodes, E=1.6M edges, D 128->128->64, G=64 graphs.
// Round 4: round-3 segmented pool, with batch correctly read as int32
// (harness converts integer inputs to int32 — reading int64 was OOB).

#define DIN 128
#define DH  128
#define DOUTC 64

// ---------------- small utility kernels ----------------

__global__ void zero_i32_kernel(int* __restrict__ p, int n) {
    int i = blockIdx.x * blockDim.x + threadIdx.x;
    if (i < n) p[i] = 0;
}

__global__ void zero_f32_kernel(float* __restrict__ p, int n) {
    int i = blockIdx.x * blockDim.x + threadIdx.x;
    if (i < n) p[i] = 0.0f;
}

__global__ void deg_count_kernel(int* __restrict__ cnt, const int* __restrict__ dst, int e) {
    int i = blockIdx.x * blockDim.x + threadIdx.x;
    if (i < e) atomicAdd(&cnt[dst[i]], 1);
}

// dinv[i] = rsqrt(in_degree + 1)   (self-loop included)
__global__ void dinv_kernel(float* __restrict__ dinv, const int* __restrict__ cnt, int n) {
    int i = blockIdx.x * blockDim.x + threadIdx.x;
    if (i < n) dinv[i] = rsqrtf((float)(cnt[i] + 1));
}

// ---------------- prefix scan (exclusive) over deg -> row_ptr ----------------
__global__ __launch_bounds__(256) void scan1_kernel(const int* __restrict__ deg,
                                                    int* __restrict__ excl,
                                                    int* __restrict__ blockSums, int n) {
    __shared__ int sh[256];
    const int tid = threadIdx.x;
    const int base = blockIdx.x * 1024 + tid * 4;
    int v[4];
    #pragma unroll
    for (int j = 0; j < 4; ++j) v[j] = (base + j < n) ? deg[base + j] : 0;
    int tsum = v[0] + v[1] + v[2] + v[3];
    sh[tid] = tsum;
    __syncthreads();
    for (int off = 1; off < 256; off <<= 1) {
        int add = (tid >= off) ? sh[tid - off] : 0;
        __syncthreads();
        sh[tid] += add;
        __syncthreads();
    }
    int texcl = sh[tid] - tsum;
    int run = texcl;
    #pragma unroll
    for (int j = 0; j < 4; ++j) {
        if (base + j < n) excl[base + j] = run;
        run += v[j];
    }
    if (tid == 255) blockSums[blockIdx.x] = sh[255];
}

__global__ void scan2_kernel(int* __restrict__ blockSums, int nb) {
    if (blockIdx.x == 0 && threadIdx.x == 0) {
        int run = 0;
        for (int i = 0; i < nb; ++i) {
            int t = blockSums[i];
            blockSums[i] = run;
            run += t;
        }
    }
}

__global__ void scan3_kernel(int* __restrict__ row_ptr, const int* __restrict__ blockSums,
                             int n, int e_total) {
    int i = blockIdx.x * blockDim.x + threadIdx.x;
    if (i < n) row_ptr[i] += blockSums[i >> 10];
    if (i == 0) row_ptr[n] = e_total;
}

// scatter edges into CSR: epack[pos] = {src, dinv[src]*dinv[dst]}
__global__ void scatter_kernel(const int* __restrict__ src, const int* __restrict__ dst,
                               const float* __restrict__ dinv, const int* __restrict__ row_ptr,
                               int* __restrict__ cursor, int2* __restrict__ ep, int e_total) {
    int e = blockIdx.x * blockDim.x + threadIdx.x;
    if (e >= e_total) return;
    int s = src[e];
    int d = dst[e];
    int pos = row_ptr[d] + atomicAdd(&cursor[d], 1);
    ep[pos] = make_int2(s, __float_as_int(dinv[s] * dinv[d]));
}

// ---------------- GEMM: Y[n][DOUT] = X[n][128] * W[128][DOUT] ----------------
template <int DOUT>
__global__ __launch_bounds__(256) void gemm_k128(const float* __restrict__ X,
                                                 const float* __restrict__ W,
                                                 float* __restrict__ Y, int n) {
    constexpr int K = 128;
    constexpr int TR = 64;
    constexpr int COLV = DOUT / 4;
    constexpr int RS = 256 / COLV;
    constexpr int RPT = TR / RS;

    __shared__ float xs[TR][K];

    const int tid = threadIdx.x;
    const int row0 = blockIdx.x * TR;

    #pragma unroll
    for (int i = 0; i < 8; ++i) {
        int idx = i * 256 + tid;
        int r = idx >> 5;
        int c = idx & 31;
        int gr = row0 + r;
        float4 v = make_float4(0.f, 0.f, 0.f, 0.f);
        if (gr < n) v = reinterpret_cast<const float4*>(X)[(size_t)gr * 32 + c];
        reinterpret_cast<float4*>(&xs[0][0])[idx] = v;
    }
    __syncthreads();

    const int col = tid % COLV;
    const int rslot = tid / COLV;

    float4 acc[RPT];
    #pragma unroll
    for (int r = 0; r < RPT; ++r) acc[r] = make_float4(0.f, 0.f, 0.f, 0.f);

    #pragma unroll 4
    for (int k = 0; k < K; ++k) {
        float4 w = reinterpret_cast<const float4*>(W)[k * COLV + col];
        #pragma unroll
        for (int r = 0; r < RPT; ++r) {
            float xv = xs[rslot + r * RS][k];
            acc[r].x += xv * w.x;
            acc[r].y += xv * w.y;
            acc[r].z += xv * w.z;
            acc[r].w += xv * w.w;
        }
    }

    #pragma unroll
    for (int r = 0; r < RPT; ++r) {
        int gr = row0 + rslot + r * RS;
        if (gr < n) reinterpret_cast<float4*>(Y)[(size_t)gr * COLV + col] = acc[r];
    }
}

// ---------------- fused CSR aggregation + selfloop + bias + relu ----------------
template <int D>
__global__ __launch_bounds__(256) void agg_relu_kernel(const float* __restrict__ XW,
                                                       const int2* __restrict__ ep,
                                                       const int* __restrict__ row_ptr,
                                                       const float* __restrict__ dinv,
                                                       const float* __restrict__ bias,
                                                       float* __restrict__ OUT, int n) {
    const int tid = threadIdx.x;
    const int node = (blockIdx.x * 256 + tid) >> 6;
    const int lane = tid & 63;
    if (node >= n) return;

    const int start = row_ptr[node];
    const int end = row_ptr[node + 1];

    if constexpr (D == 128) {
        const float2* XW2 = reinterpret_cast<const float2*>(XW);
        float di = dinv[node];
        float sl = di * di;
        float2 v = XW2[(size_t)node * 64 + lane];
        float ax = v.x * sl, ay = v.y * sl;
        for (int p = start; p < end; ++p) {
            int2 m = ep[p];
            float w = __int_as_float(m.y);
            float2 u = XW2[(size_t)m.x * 64 + lane];
            ax += u.x * w;
            ay += u.y * w;
        }
        float2 b = reinterpret_cast<const float2*>(bias)[lane];
        float2 o;
        o.x = fmaxf(ax + b.x, 0.f);
        o.y = fmaxf(ay + b.y, 0.f);
        reinterpret_cast<float2*>(OUT)[(size_t)node * 64 + lane] = o;
    } else {
        float di = dinv[node];
        float sl = di * di;
        float acc = XW[(size_t)node * D + lane] * sl;
        for (int p = start; p < end; ++p) {
            int2 m = ep[p];
            float w = __int_as_float(m.y);
            acc += XW[(size_t)m.x * D + lane] * w;
        }
        float o = fmaxf(acc + bias[lane], 0.f);
        OUT[(size_t)node * D + lane] = o;
    }
}

// ---------------- pooling: segmented reduction over sorted batch ----------------
// One wave per POOL_CHUNK consecutive nodes; lane = dim (DOUTC==64).
// Accumulate in-register, flush to sums[g][lane] only on graph-id change /
// chunk end. batch sorted => very few flushes.
#define POOL_CHUNK 64

__global__ __launch_bounds__(256) void pool_seg_kernel(const float* __restrict__ H,
                                                       const int* __restrict__ batch,
                                                       float* __restrict__ sums,
                                                       float* __restrict__ cnt, int n) {
    const int wave = (blockIdx.x * 256 + threadIdx.x) >> 6;
    const int lane = threadIdx.x & 63;
    int i0 = wave * POOL_CHUNK;
    if (i0 >= n) return;
    int i1 = min(i0 + POOL_CHUNK, n);

    int g = batch[i0];
    float acc = 0.0f;
    int segn = 0;
    for (int i = i0; i < i1; ++i) {
        int gi = batch[i];
        if (gi != g) {
            unsafeAtomicAdd(&sums[g * DOUTC + lane], acc);
            if (lane == 0) unsafeAtomicAdd(&cnt[g], (float)segn);
            g = gi;
            acc = 0.0f;
            segn = 0;
        }
        acc += H[(size_t)i * DOUTC + lane];
        ++segn;
    }
    unsafeAtomicAdd(&sums[g * DOUTC + lane], acc);
    if (lane == 0) unsafeAtomicAdd(&cnt[g], (float)segn);
}

__global__ void pool_finish_kernel(const float* __restrict__ sums, const float* __restrict__ cnt,
                                   float* __restrict__ out, int g_total) {
    int t = blockIdx.x * blockDim.x + threadIdx.x;
    if (t >= g_total * DOUTC) return;
    int g = t >> 6;
    out[t] = sums[t] / fmaxf(cnt[g], 1.0f);
}

// ---------------- launch ----------------

extern "C" void kernel_launch(void* const* d_in, const int* in_sizes, int n_in,
                              void* d_out, int out_size, void* d_ws, size_t ws_size,
                              hipStream_t stream) {
    const float* x    = (const float*)d_in[0];
    const int*   ei   = (const int*)d_in[1];   // [2][E], int32 per harness convention
    const int*   batch= (const int*)d_in[2];   // int32 per harness convention
    const float* W1   = (const float*)d_in[3];
    const float* b1   = (const float*)d_in[4];
    const float* W2   = (const float*)d_in[5];
    const float* b2   = (const float*)d_in[6];
    float* out = (float*)d_out;

    const int N = in_sizes[0] / DIN;
    const int E = in_sizes[1] / 2;
    const int G = out_size / DOUTC;

    const int* esrc = ei;
    const int* edst = ei + E;

    // workspace carve-out (256B aligned)
    char* ws = (char*)d_ws;
    size_t off = 0;
    auto alloc = [&](size_t bytes) -> void* {
        void* p = ws + off;
        off = (off + bytes + 255) & ~(size_t)255;
        return p;
    };
    float* dinv    = (float*)alloc((size_t)N * 4);
    int*   row_ptr = (int*)alloc((size_t)(N + 1) * 4);
    int*   cursor  = (int*)alloc((size_t)N * 4);
    int*   blockSums = (int*)alloc(1024 * 4);
    int2*  epack   = (int2*)alloc((size_t)E * 8);
    float* bufA    = (float*)alloc((size_t)N * DH * 4);
    float* bufB    = (float*)alloc((size_t)N * DH * 4);
    float* sums    = (float*)alloc((size_t)G * DOUTC * 4 + (size_t)G * 4);
    float* cnt     = sums + G * DOUTC;

    const int B = 256;
    auto cdiv = [](long long a, long long b) { return (int)((a + b - 1) / b); };
    const int nScanBlocks = cdiv(N, 1024);

    // ---- CSR build ----
    zero_i32_kernel<<<cdiv(N, B), B, 0, stream>>>(cursor, N);
    zero_f32_kernel<<<cdiv(G * DOUTC + G, B), B, 0, stream>>>(sums, G * DOUTC + G);
    deg_count_kernel<<<cdiv(E, B), B, 0, stream>>>(cursor, edst, E);
    dinv_kernel<<<cdiv(N, B), B, 0, stream>>>(dinv, cursor, N);
    scan1_kernel<<<nScanBlocks, B, 0, stream>>>(cursor, row_ptr, blockSums, N);
    scan2_kernel<<<1, 64, 0, stream>>>(blockSums, nScanBlocks);
    scan3_kernel<<<cdiv(N, B), B, 0, stream>>>(row_ptr, blockSums, N, E);
    zero_i32_kernel<<<cdiv(N, B), B, 0, stream>>>(cursor, N);
    scatter_kernel<<<cdiv(E, B), B, 0, stream>>>(esrc, edst, dinv, row_ptr, cursor, epack, E);

    // ---- layer 1: h1 = relu(agg(x@W1) + b1) ----
    gemm_k128<DH><<<cdiv(N, 64), B, 0, stream>>>(x, W1, bufA, N);
    agg_relu_kernel<DH><<<cdiv(N, 4), B, 0, stream>>>(bufA, epack, row_ptr, dinv, b1, bufB, N);

    // ---- layer 2: h2 = relu(agg(h1@W2) + b2) ----
    gemm_k128<DOUTC><<<cdiv(N, 64), B, 0, stream>>>(bufB, W2, bufA, N);
    agg_relu_kernel<DOUTC><<<cdiv(N, 4), B, 0, stream>>>(bufA, epack, row_ptr, dinv, b2, bufB, N);

    // ---- pool ----
    const int nPoolWaves = cdiv(N, POOL_CHUNK);
    pool_seg_kernel<<<cdiv((long long)nPoolWaves * 64, B), B, 0, stream>>>(bufB, batch, sums, cnt, N);
    pool_finish_kernel<<<cdiv(G * DOUTC, B), B, 0, stream>>>(sums, cnt, out, G);
}

// Round 5
// 480.728 us; speedup vs baseline: 10.6254x; 1.2575x over previous
//
#include <hip/hip_runtime.h>
#include <hip/hip_bf16.h>

// GCN encoder: 2x GCNConv(relu) + global mean pool.
// N=100000 nodes, E=1.6M edges, D 128->128->64, G=64 graphs.
// Round 5: 4x unrolled edge-gather loop in agg_relu (MLP for latency-bound gathers).

#define DIN 128
#define DH  128
#define DOUTC 64

// ---------------- small utility kernels ----------------

__global__ void zero_i32_kernel(int* __restrict__ p, int n) {
    int i = blockIdx.x * blockDim.x + threadIdx.x;
    if (i < n) p[i] = 0;
}

__global__ void zero_f32_kernel(float* __restrict__ p, int n) {
    int i = blockIdx.x * blockDim.x + threadIdx.x;
    if (i < n) p[i] = 0.0f;
}

__global__ void deg_count_kernel(int* __restrict__ cnt, const int* __restrict__ dst, int e) {
    int i = blockIdx.x * blockDim.x + threadIdx.x;
    if (i < e) atomicAdd(&cnt[dst[i]], 1);
}

// dinv[i] = rsqrt(in_degree + 1)   (self-loop included)
__global__ void dinv_kernel(float* __restrict__ dinv, const int* __restrict__ cnt, int n) {
    int i = blockIdx.x * blockDim.x + threadIdx.x;
    if (i < n) dinv[i] = rsqrtf((float)(cnt[i] + 1));
}

// ---------------- prefix scan (exclusive) over deg -> row_ptr ----------------
__global__ __launch_bounds__(256) void scan1_kernel(const int* __restrict__ deg,
                                                    int* __restrict__ excl,
                                                    int* __restrict__ blockSums, int n) {
    __shared__ int sh[256];
    const int tid = threadIdx.x;
    const int base = blockIdx.x * 1024 + tid * 4;
    int v[4];
    #pragma unroll
    for (int j = 0; j < 4; ++j) v[j] = (base + j < n) ? deg[base + j] : 0;
    int tsum = v[0] + v[1] + v[2] + v[3];
    sh[tid] = tsum;
    __syncthreads();
    for (int off = 1; off < 256; off <<= 1) {
        int add = (tid >= off) ? sh[tid - off] : 0;
        __syncthreads();
        sh[tid] += add;
        __syncthreads();
    }
    int texcl = sh[tid] - tsum;
    int run = texcl;
    #pragma unroll
    for (int j = 0; j < 4; ++j) {
        if (base + j < n) excl[base + j] = run;
        run += v[j];
    }
    if (tid == 255) blockSums[blockIdx.x] = sh[255];
}

__global__ void scan2_kernel(int* __restrict__ blockSums, int nb) {
    if (blockIdx.x == 0 && threadIdx.x == 0) {
        int run = 0;
        for (int i = 0; i < nb; ++i) {
            int t = blockSums[i];
            blockSums[i] = run;
            run += t;
        }
    }
}

__global__ void scan3_kernel(int* __restrict__ row_ptr, const int* __restrict__ blockSums,
                             int n, int e_total) {
    int i = blockIdx.x * blockDim.x + threadIdx.x;
    if (i < n) row_ptr[i] += blockSums[i >> 10];
    if (i == 0) row_ptr[n] = e_total;
}

// scatter edges into CSR: epack[pos] = {src, dinv[src]*dinv[dst]}
__global__ void scatter_kernel(const int* __restrict__ src, const int* __restrict__ dst,
                               const float* __restrict__ dinv, const int* __restrict__ row_ptr,
                               int* __restrict__ cursor, int2* __restrict__ ep, int e_total) {
    int e = blockIdx.x * blockDim.x + threadIdx.x;
    if (e >= e_total) return;
    int s = src[e];
    int d = dst[e];
    int pos = row_ptr[d] + atomicAdd(&cursor[d], 1);
    ep[pos] = make_int2(s, __float_as_int(dinv[s] * dinv[d]));
}

// ---------------- GEMM: Y[n][DOUT] = X[n][128] * W[128][DOUT] ----------------
template <int DOUT>
__global__ __launch_bounds__(256) void gemm_k128(const float* __restrict__ X,
                                                 const float* __restrict__ W,
                                                 float* __restrict__ Y, int n) {
    constexpr int K = 128;
    constexpr int TR = 64;
    constexpr int COLV = DOUT / 4;
    constexpr int RS = 256 / COLV;
    constexpr int RPT = TR / RS;

    __shared__ float xs[TR][K];

    const int tid = threadIdx.x;
    const int row0 = blockIdx.x * TR;

    #pragma unroll
    for (int i = 0; i < 8; ++i) {
        int idx = i * 256 + tid;
        int r = idx >> 5;
        int c = idx & 31;
        int gr = row0 + r;
        float4 v = make_float4(0.f, 0.f, 0.f, 0.f);
        if (gr < n) v = reinterpret_cast<const float4*>(X)[(size_t)gr * 32 + c];
        reinterpret_cast<float4*>(&xs[0][0])[idx] = v;
    }
    __syncthreads();

    const int col = tid % COLV;
    const int rslot = tid / COLV;

    float4 acc[RPT];
    #pragma unroll
    for (int r = 0; r < RPT; ++r) acc[r] = make_float4(0.f, 0.f, 0.f, 0.f);

    #pragma unroll 4
    for (int k = 0; k < K; ++k) {
        float4 w = reinterpret_cast<const float4*>(W)[k * COLV + col];
        #pragma unroll
        for (int r = 0; r < RPT; ++r) {
            float xv = xs[rslot + r * RS][k];
            acc[r].x += xv * w.x;
            acc[r].y += xv * w.y;
            acc[r].z += xv * w.z;
            acc[r].w += xv * w.w;
        }
    }

    #pragma unroll
    for (int r = 0; r < RPT; ++r) {
        int gr = row0 + rslot + r * RS;
        if (gr < n) reinterpret_cast<float4*>(Y)[(size_t)gr * COLV + col] = acc[r];
    }
}

// ---------------- fused CSR aggregation + selfloop + bias + relu ----------------
// One wave per node; edge loop unrolled 4x so 4 independent ep-loads + 4
// independent row-gathers are in flight per wave (latency hiding).
template <int D>
__global__ __launch_bounds__(256) void agg_relu_kernel(const float* __restrict__ XW,
                                                       const int2* __restrict__ ep,
                                                       const int* __restrict__ row_ptr,
                                                       const float* __restrict__ dinv,
                                                       const float* __restrict__ bias,
                                                       float* __restrict__ OUT, int n) {
    const int tid = threadIdx.x;
    const int node = (blockIdx.x * 256 + tid) >> 6;
    const int lane = tid & 63;
    if (node >= n) return;

    const int start = row_ptr[node];
    const int end = row_ptr[node + 1];

    if constexpr (D == 128) {
        const float2* XW2 = reinterpret_cast<const float2*>(XW);
        float di = dinv[node];
        float sl = di * di;
        float2 v = XW2[(size_t)node * 64 + lane];
        float ax = v.x * sl, ay = v.y * sl;
        float bx = 0.f, by = 0.f;   // second accumulator pair for ILP

        int p = start;
        for (; p + 4 <= end; p += 4) {
            int2 m0 = ep[p + 0];
            int2 m1 = ep[p + 1];
            int2 m2 = ep[p + 2];
            int2 m3 = ep[p + 3];
            float2 u0 = XW2[(size_t)m0.x * 64 + lane];
            float2 u1 = XW2[(size_t)m1.x * 64 + lane];
            float2 u2 = XW2[(size_t)m2.x * 64 + lane];
            float2 u3 = XW2[(size_t)m3.x * 64 + lane];
            float w0 = __int_as_float(m0.y);
            float w1 = __int_as_float(m1.y);
            float w2 = __int_as_float(m2.y);
            float w3 = __int_as_float(m3.y);
            ax += u0.x * w0; ay += u0.y * w0;
            bx += u1.x * w1; by += u1.y * w1;
            ax += u2.x * w2; ay += u2.y * w2;
            bx += u3.x * w3; by += u3.y * w3;
        }
        for (; p < end; ++p) {
            int2 m = ep[p];
            float w = __int_as_float(m.y);
            float2 u = XW2[(size_t)m.x * 64 + lane];
            ax += u.x * w;
            ay += u.y * w;
        }
        ax += bx; ay += by;

        float2 b = reinterpret_cast<const float2*>(bias)[lane];
        float2 o;
        o.x = fmaxf(ax + b.x, 0.f);
        o.y = fmaxf(ay + b.y, 0.f);
        reinterpret_cast<float2*>(OUT)[(size_t)node * 64 + lane] = o;
    } else {
        float di = dinv[node];
        float sl = di * di;
        float acc0 = XW[(size_t)node * D + lane] * sl;
        float acc1 = 0.f;

        int p = start;
        for (; p + 4 <= end; p += 4) {
            int2 m0 = ep[p + 0];
            int2 m1 = ep[p + 1];
            int2 m2 = ep[p + 2];
            int2 m3 = ep[p + 3];
            float u0 = XW[(size_t)m0.x * D + lane];
            float u1 = XW[(size_t)m1.x * D + lane];
            float u2 = XW[(size_t)m2.x * D + lane];
            float u3 = XW[(size_t)m3.x * D + lane];
            acc0 += u0 * __int_as_float(m0.y);
            acc1 += u1 * __int_as_float(m1.y);
            acc0 += u2 * __int_as_float(m2.y);
            acc1 += u3 * __int_as_float(m3.y);
        }
        for (; p < end; ++p) {
            int2 m = ep[p];
            acc0 += XW[(size_t)m.x * D + lane] * __int_as_float(m.y);
        }
        acc0 += acc1;

        float o = fmaxf(acc0 + bias[lane], 0.f);
        OUT[(size_t)node * D + lane] = o;
    }
}

// ---------------- pooling: segmented reduction over sorted batch ----------------
#define POOL_CHUNK 64

__global__ __launch_bounds__(256) void pool_seg_kernel(const float* __restrict__ H,
                                                       const int* __restrict__ batch,
                                                       float* __restrict__ sums,
                                                       float* __restrict__ cnt, int n) {
    const int wave = (blockIdx.x * 256 + threadIdx.x) >> 6;
    const int lane = threadIdx.x & 63;
    int i0 = wave * POOL_CHUNK;
    if (i0 >= n) return;
    int i1 = min(i0 + POOL_CHUNK, n);

    int g = batch[i0];
    float acc = 0.0f;
    int segn = 0;
    for (int i = i0; i < i1; ++i) {
        int gi = batch[i];
        if (gi != g) {
            unsafeAtomicAdd(&sums[g * DOUTC + lane], acc);
            if (lane == 0) unsafeAtomicAdd(&cnt[g], (float)segn);
            g = gi;
            acc = 0.0f;
            segn = 0;
        }
        acc += H[(size_t)i * DOUTC + lane];
        ++segn;
    }
    unsafeAtomicAdd(&sums[g * DOUTC + lane], acc);
    if (lane == 0) unsafeAtomicAdd(&cnt[g], (float)segn);
}

__global__ void pool_finish_kernel(const float* __restrict__ sums, const float* __restrict__ cnt,
                                   float* __restrict__ out, int g_total) {
    int t = blockIdx.x * blockDim.x + threadIdx.x;
    if (t >= g_total * DOUTC) return;
    int g = t >> 6;
    out[t] = sums[t] / fmaxf(cnt[g], 1.0f);
}

// ---------------- launch ----------------

extern "C" void kernel_launch(void* const* d_in, const int* in_sizes, int n_in,
                              void* d_out, int out_size, void* d_ws, size_t ws_size,
                              hipStream_t stream) {
    const float* x    = (const float*)d_in[0];
    const int*   ei   = (const int*)d_in[1];   // [2][E], int32 per harness convention
    const int*   batch= (const int*)d_in[2];   // int32 per harness convention
    const float* W1   = (const float*)d_in[3];
    const float* b1   = (const float*)d_in[4];
    const float* W2   = (const float*)d_in[5];
    const float* b2   = (const float*)d_in[6];
    float* out = (float*)d_out;

    const int N = in_sizes[0] / DIN;
    const int E = in_sizes[1] / 2;
    const int G = out_size / DOUTC;

    const int* esrc = ei;
    const int* edst = ei + E;

    // workspace carve-out (256B aligned)
    char* ws = (char*)d_ws;
    size_t off = 0;
    auto alloc = [&](size_t bytes) -> void* {
        void* p = ws + off;
        off = (off + bytes + 255) & ~(size_t)255;
        return p;
    };
    float* dinv    = (float*)alloc((size_t)N * 4);
    int*   row_ptr = (int*)alloc((size_t)(N + 1) * 4);
    int*   cursor  = (int*)alloc((size_t)N * 4);
    int*   blockSums = (int*)alloc(1024 * 4);
    int2*  epack   = (int2*)alloc((size_t)E * 8);
    float* bufA    = (float*)alloc((size_t)N * DH * 4);
    float* bufB    = (float*)alloc((size_t)N * DH * 4);
    float* sums    = (float*)alloc((size_t)G * DOUTC * 4 + (size_t)G * 4);
    float* cnt     = sums + G * DOUTC;

    const int B = 256;
    auto cdiv = [](long long a, long long b) { return (int)((a + b - 1) / b); };
    const int nScanBlocks = cdiv(N, 1024);

    // ---- CSR build ----
    zero_i32_kernel<<<cdiv(N, B), B, 0, stream>>>(cursor, N);
    zero_f32_kernel<<<cdiv(G * DOUTC + G, B), B, 0, stream>>>(sums, G * DOUTC + G);
    deg_count_kernel<<<cdiv(E, B), B, 0, stream>>>(cursor, edst, E);
    dinv_kernel<<<cdiv(N, B), B, 0, stream>>>(dinv, cursor, N);
    scan1_kernel<<<nScanBlocks, B, 0, stream>>>(cursor, row_ptr, blockSums, N);
    scan2_kernel<<<1, 64, 0, stream>>>(blockSums, nScanBlocks);
    scan3_kernel<<<cdiv(N, B), B, 0, stream>>>(row_ptr, blockSums, N, E);
    zero_i32_kernel<<<cdiv(N, B), B, 0, stream>>>(cursor, N);
    scatter_kernel<<<cdiv(E, B), B, 0, stream>>>(esrc, edst, dinv, row_ptr, cursor, epack, E);

    // ---- layer 1: h1 = relu(agg(x@W1) + b1) ----
    gemm_k128<DH><<<cdiv(N, 64), B, 0, stream>>>(x, W1, bufA, N);
    agg_relu_kernel<DH><<<cdiv(N, 4), B, 0, stream>>>(bufA, epack, row_ptr, dinv, b1, bufB, N);

    // ---- layer 2: h2 = relu(agg(h1@W2) + b2) ----
    gemm_k128<DOUTC><<<cdiv(N, 64), B, 0, stream>>>(bufB, W2, bufA, N);
    agg_relu_kernel<DOUTC><<<cdiv(N, 4), B, 0, stream>>>(bufA, epack, row_ptr, dinv, b2, bufB, N);

    // ---- pool ----
    const int nPoolWaves = cdiv(N, POOL_CHUNK);
    pool_seg_kernel<<<cdiv((long long)nPoolWaves * 64, B), B, 0, stream>>>(bufB, batch, sums, cnt, N);
    pool_finish_kernel<<<cdiv(G * DOUTC, B), B, 0, stream>>>(sums, cnt, out, G);
}

// Round 6
// 428.441 us; speedup vs baseline: 11.9221x; 1.1220x over previous
//
#include <hip/hip_runtime.h>
#include <hip/hip_bf16.h>

// GCN encoder: 2x GCNConv(relu) + global mean pool.
// N=100000 nodes, E=1.6M edges, D 128->128->64, G=64 graphs.
// Round 6: XW buffers in bf16 (halves edge-gather traffic); f32 accumulation.

#define DIN 128
#define DH  128
#define DOUTC 64

// bf16 helpers (RNE pack, shift unpack)
__device__ inline unsigned short f2bf(float f) {
    union { float f; unsigned u; } v; v.f = f;
    unsigned r = v.u + 0x7FFF + ((v.u >> 16) & 1);
    return (unsigned short)(r >> 16);
}
__device__ inline float bf_lo(unsigned u) { return __uint_as_float(u << 16); }
__device__ inline float bf_hi(unsigned u) { return __uint_as_float(u & 0xFFFF0000u); }

// ---------------- small utility kernels ----------------

__global__ void zero_i32_kernel(int* __restrict__ p, int n) {
    int i = blockIdx.x * blockDim.x + threadIdx.x;
    if (i < n) p[i] = 0;
}

__global__ void zero_f32_kernel(float* __restrict__ p, int n) {
    int i = blockIdx.x * blockDim.x + threadIdx.x;
    if (i < n) p[i] = 0.0f;
}

__global__ void deg_count_kernel(int* __restrict__ cnt, const int* __restrict__ dst, int e) {
    int i = blockIdx.x * blockDim.x + threadIdx.x;
    if (i < e) atomicAdd(&cnt[dst[i]], 1);
}

// dinv[i] = rsqrt(in_degree + 1)   (self-loop included)
__global__ void dinv_kernel(float* __restrict__ dinv, const int* __restrict__ cnt, int n) {
    int i = blockIdx.x * blockDim.x + threadIdx.x;
    if (i < n) dinv[i] = rsqrtf((float)(cnt[i] + 1));
}

// ---------------- prefix scan (exclusive) over deg -> row_ptr ----------------
__global__ __launch_bounds__(256) void scan1_kernel(const int* __restrict__ deg,
                                                    int* __restrict__ excl,
                                                    int* __restrict__ blockSums, int n) {
    __shared__ int sh[256];
    const int tid = threadIdx.x;
    const int base = blockIdx.x * 1024 + tid * 4;
    int v[4];
    #pragma unroll
    for (int j = 0; j < 4; ++j) v[j] = (base + j < n) ? deg[base + j] : 0;
    int tsum = v[0] + v[1] + v[2] + v[3];
    sh[tid] = tsum;
    __syncthreads();
    for (int off = 1; off < 256; off <<= 1) {
        int add = (tid >= off) ? sh[tid - off] : 0;
        __syncthreads();
        sh[tid] += add;
        __syncthreads();
    }
    int texcl = sh[tid] - tsum;
    int run = texcl;
    #pragma unroll
    for (int j = 0; j < 4; ++j) {
        if (base + j < n) excl[base + j] = run;
        run += v[j];
    }
    if (tid == 255) blockSums[blockIdx.x] = sh[255];
}

__global__ void scan2_kernel(int* __restrict__ blockSums, int nb) {
    if (blockIdx.x == 0 && threadIdx.x == 0) {
        int run = 0;
        for (int i = 0; i < nb; ++i) {
            int t = blockSums[i];
            blockSums[i] = run;
            run += t;
        }
    }
}

__global__ void scan3_kernel(int* __restrict__ row_ptr, const int* __restrict__ blockSums,
                             int n, int e_total) {
    int i = blockIdx.x * blockDim.x + threadIdx.x;
    if (i < n) row_ptr[i] += blockSums[i >> 10];
    if (i == 0) row_ptr[n] = e_total;
}

// scatter edges into CSR: epack[pos] = {src, dinv[src]*dinv[dst]}
__global__ void scatter_kernel(const int* __restrict__ src, const int* __restrict__ dst,
                               const float* __restrict__ dinv, const int* __restrict__ row_ptr,
                               int* __restrict__ cursor, int2* __restrict__ ep, int e_total) {
    int e = blockIdx.x * blockDim.x + threadIdx.x;
    if (e >= e_total) return;
    int s = src[e];
    int d = dst[e];
    int pos = row_ptr[d] + atomicAdd(&cursor[d], 1);
    ep[pos] = make_int2(s, __float_as_int(dinv[s] * dinv[d]));
}

// ---------------- GEMM: Y[n][DOUT] = X[n][128] * W[128][DOUT], bf16 output ----
template <int DOUT>
__global__ __launch_bounds__(256) void gemm_k128_bf16out(const float* __restrict__ X,
                                                         const float* __restrict__ W,
                                                         unsigned short* __restrict__ Y, int n) {
    constexpr int K = 128;
    constexpr int TR = 64;
    constexpr int COLV = DOUT / 4;
    constexpr int RS = 256 / COLV;
    constexpr int RPT = TR / RS;

    __shared__ float xs[TR][K];

    const int tid = threadIdx.x;
    const int row0 = blockIdx.x * TR;

    #pragma unroll
    for (int i = 0; i < 8; ++i) {
        int idx = i * 256 + tid;
        int r = idx >> 5;
        int c = idx & 31;
        int gr = row0 + r;
        float4 v = make_float4(0.f, 0.f, 0.f, 0.f);
        if (gr < n) v = reinterpret_cast<const float4*>(X)[(size_t)gr * 32 + c];
        reinterpret_cast<float4*>(&xs[0][0])[idx] = v;
    }
    __syncthreads();

    const int col = tid % COLV;
    const int rslot = tid / COLV;

    float4 acc[RPT];
    #pragma unroll
    for (int r = 0; r < RPT; ++r) acc[r] = make_float4(0.f, 0.f, 0.f, 0.f);

    #pragma unroll 4
    for (int k = 0; k < K; ++k) {
        float4 w = reinterpret_cast<const float4*>(W)[k * COLV + col];
        #pragma unroll
        for (int r = 0; r < RPT; ++r) {
            float xv = xs[rslot + r * RS][k];
            acc[r].x += xv * w.x;
            acc[r].y += xv * w.y;
            acc[r].z += xv * w.z;
            acc[r].w += xv * w.w;
        }
    }

    #pragma unroll
    for (int r = 0; r < RPT; ++r) {
        int gr = row0 + rslot + r * RS;
        if (gr < n) {
            ushort4 st;
            st.x = f2bf(acc[r].x);
            st.y = f2bf(acc[r].y);
            st.z = f2bf(acc[r].z);
            st.w = f2bf(acc[r].w);
            reinterpret_cast<ushort4*>(Y)[(size_t)gr * COLV + col] = st;
        }
    }
}

// ---------------- fused CSR aggregation + selfloop + bias + relu ----------------
// One wave per node; 4x unrolled edge loop; XW is bf16 (256B/128B rows),
// accumulation in f32. OUT stays f32.
template <int D>
__global__ __launch_bounds__(256) void agg_relu_kernel(const unsigned short* __restrict__ XW,
                                                       const int2* __restrict__ ep,
                                                       const int* __restrict__ row_ptr,
                                                       const float* __restrict__ dinv,
                                                       const float* __restrict__ bias,
                                                       float* __restrict__ OUT, int n) {
    const int tid = threadIdx.x;
    const int node = (blockIdx.x * 256 + tid) >> 6;
    const int lane = tid & 63;
    if (node >= n) return;

    const int start = row_ptr[node];
    const int end = row_ptr[node + 1];

    if constexpr (D == 128) {
        const unsigned* XWu = reinterpret_cast<const unsigned*>(XW);  // 64 uints/row
        float di = dinv[node];
        float sl = di * di;
        unsigned rv = XWu[(size_t)node * 64 + lane];
        float ax = bf_lo(rv) * sl, ay = bf_hi(rv) * sl;
        float bx = 0.f, by = 0.f;

        int p = start;
        for (; p + 4 <= end; p += 4) {
            int2 m0 = ep[p + 0];
            int2 m1 = ep[p + 1];
            int2 m2 = ep[p + 2];
            int2 m3 = ep[p + 3];
            unsigned u0 = XWu[(size_t)m0.x * 64 + lane];
            unsigned u1 = XWu[(size_t)m1.x * 64 + lane];
            unsigned u2 = XWu[(size_t)m2.x * 64 + lane];
            unsigned u3 = XWu[(size_t)m3.x * 64 + lane];
            float w0 = __int_as_float(m0.y);
            float w1 = __int_as_float(m1.y);
            float w2 = __int_as_float(m2.y);
            float w3 = __int_as_float(m3.y);
            ax += bf_lo(u0) * w0; ay += bf_hi(u0) * w0;
            bx += bf_lo(u1) * w1; by += bf_hi(u1) * w1;
            ax += bf_lo(u2) * w2; ay += bf_hi(u2) * w2;
            bx += bf_lo(u3) * w3; by += bf_hi(u3) * w3;
        }
        for (; p < end; ++p) {
            int2 m = ep[p];
            float w = __int_as_float(m.y);
            unsigned u = XWu[(size_t)m.x * 64 + lane];
            ax += bf_lo(u) * w;
            ay += bf_hi(u) * w;
        }
        ax += bx; ay += by;

        float2 b = reinterpret_cast<const float2*>(bias)[lane];
        float2 o;
        o.x = fmaxf(ax + b.x, 0.f);
        o.y = fmaxf(ay + b.y, 0.f);
        reinterpret_cast<float2*>(OUT)[(size_t)node * 64 + lane] = o;
    } else {
        float di = dinv[node];
        float sl = di * di;
        float acc0 = __uint_as_float(((unsigned)XW[(size_t)node * D + lane]) << 16) * sl;
        float acc1 = 0.f;

        int p = start;
        for (; p + 4 <= end; p += 4) {
            int2 m0 = ep[p + 0];
            int2 m1 = ep[p + 1];
            int2 m2 = ep[p + 2];
            int2 m3 = ep[p + 3];
            float u0 = __uint_as_float(((unsigned)XW[(size_t)m0.x * D + lane]) << 16);
            float u1 = __uint_as_float(((unsigned)XW[(size_t)m1.x * D + lane]) << 16);
            float u2 = __uint_as_float(((unsigned)XW[(size_t)m2.x * D + lane]) << 16);
            float u3 = __uint_as_float(((unsigned)XW[(size_t)m3.x * D + lane]) << 16);
            acc0 += u0 * __int_as_float(m0.y);
            acc1 += u1 * __int_as_float(m1.y);
            acc0 += u2 * __int_as_float(m2.y);
            acc1 += u3 * __int_as_float(m3.y);
        }
        for (; p < end; ++p) {
            int2 m = ep[p];
            acc0 += __uint_as_float(((unsigned)XW[(size_t)m.x * D + lane]) << 16) * __int_as_float(m.y);
        }
        acc0 += acc1;

        float o = fmaxf(acc0 + bias[lane], 0.f);
        OUT[(size_t)node * D + lane] = o;
    }
}

// ---------------- pooling: segmented reduction over sorted batch ----------------
#define POOL_CHUNK 64

__global__ __launch_bounds__(256) void pool_seg_kernel(const float* __restrict__ H,
                                                       const int* __restrict__ batch,
                                                       float* __restrict__ sums,
                                                       float* __restrict__ cnt, int n) {
    const int wave = (blockIdx.x * 256 + threadIdx.x) >> 6;
    const int lane = threadIdx.x & 63;
    int i0 = wave * POOL_CHUNK;
    if (i0 >= n) return;
    int i1 = min(i0 + POOL_CHUNK, n);

    int g = batch[i0];
    float acc = 0.0f;
    int segn = 0;
    for (int i = i0; i < i1; ++i) {
        int gi = batch[i];
        if (gi != g) {
            unsafeAtomicAdd(&sums[g * DOUTC + lane], acc);
            if (lane == 0) unsafeAtomicAdd(&cnt[g], (float)segn);
            g = gi;
            acc = 0.0f;
            segn = 0;
        }
        acc += H[(size_t)i * DOUTC + lane];
        ++segn;
    }
    unsafeAtomicAdd(&sums[g * DOUTC + lane], acc);
    if (lane == 0) unsafeAtomicAdd(&cnt[g], (float)segn);
}

__global__ void pool_finish_kernel(const float* __restrict__ sums, const float* __restrict__ cnt,
                                   float* __restrict__ out, int g_total) {
    int t = blockIdx.x * blockDim.x + threadIdx.x;
    if (t >= g_total * DOUTC) return;
    int g = t >> 6;
    out[t] = sums[t] / fmaxf(cnt[g], 1.0f);
}

// ---------------- launch ----------------

extern "C" void kernel_launch(void* const* d_in, const int* in_sizes, int n_in,
                              void* d_out, int out_size, void* d_ws, size_t ws_size,
                              hipStream_t stream) {
    const float* x    = (const float*)d_in[0];
    const int*   ei   = (const int*)d_in[1];   // [2][E], int32 per harness convention
    const int*   batch= (const int*)d_in[2];   // int32 per harness convention
    const float* W1   = (const float*)d_in[3];
    const float* b1   = (const float*)d_in[4];
    const float* W2   = (const float*)d_in[5];
    const float* b2   = (const float*)d_in[6];
    float* out = (float*)d_out;

    const int N = in_sizes[0] / DIN;
    const int E = in_sizes[1] / 2;
    const int G = out_size / DOUTC;

    const int* esrc = ei;
    const int* edst = ei + E;

    // workspace carve-out (256B aligned)
    char* ws = (char*)d_ws;
    size_t off = 0;
    auto alloc = [&](size_t bytes) -> void* {
        void* p = ws + off;
        off = (off + bytes + 255) & ~(size_t)255;
        return p;
    };
    float* dinv    = (float*)alloc((size_t)N * 4);
    int*   row_ptr = (int*)alloc((size_t)(N + 1) * 4);
    int*   cursor  = (int*)alloc((size_t)N * 4);
    int*   blockSums = (int*)alloc(1024 * 4);
    int2*  epack   = (int2*)alloc((size_t)E * 8);
    unsigned short* xwbf = (unsigned short*)alloc((size_t)N * DH * 2);  // bf16 XW
    float* bufB    = (float*)alloc((size_t)N * DH * 4);                 // h1/h2 (f32)
    float* sums    = (float*)alloc((size_t)G * DOUTC * 4 + (size_t)G * 4);
    float* cnt     = sums + G * DOUTC;

    const int B = 256;
    auto cdiv = [](long long a, long long b) { return (int)((a + b - 1) / b); };
    const int nScanBlocks = cdiv(N, 1024);

    // ---- CSR build ----
    zero_i32_kernel<<<cdiv(N, B), B, 0, stream>>>(cursor, N);
    zero_f32_kernel<<<cdiv(G * DOUTC + G, B), B, 0, stream>>>(sums, G * DOUTC + G);
    deg_count_kernel<<<cdiv(E, B), B, 0, stream>>>(cursor, edst, E);
    dinv_kernel<<<cdiv(N, B), B, 0, stream>>>(dinv, cursor, N);
    scan1_kernel<<<nScanBlocks, B, 0, stream>>>(cursor, row_ptr, blockSums, N);
    scan2_kernel<<<1, 64, 0, stream>>>(blockSums, nScanBlocks);
    scan3_kernel<<<cdiv(N, B), B, 0, stream>>>(row_ptr, blockSums, N, E);
    zero_i32_kernel<<<cdiv(N, B), B, 0, stream>>>(cursor, N);
    scatter_kernel<<<cdiv(E, B), B, 0, stream>>>(esrc, edst, dinv, row_ptr, cursor, epack, E);

    // ---- layer 1: h1 = relu(agg(bf16(x@W1)) + b1) ----
    gemm_k128_bf16out<DH><<<cdiv(N, 64), B, 0, stream>>>(x, W1, xwbf, N);
    agg_relu_kernel<DH><<<cdiv(N, 4), B, 0, stream>>>(xwbf, epack, row_ptr, dinv, b1, bufB, N);

    // ---- layer 2: h2 = relu(agg(bf16(h1@W2)) + b2) ----
    gemm_k128_bf16out<DOUTC><<<cdiv(N, 64), B, 0, stream>>>(bufB, W2, xwbf, N);
    agg_relu_kernel<DOUTC><<<cdiv(N, 4), B, 0, stream>>>(xwbf, epack, row_ptr, dinv, b2, bufB, N);

    // ---- pool ----
    const int nPoolWaves = cdiv(N, POOL_CHUNK);
    pool_seg_kernel<<<cdiv((long long)nPoolWaves * 64, B), B, 0, stream>>>(bufB, batch, sums, cnt, N);
    pool_finish_kernel<<<cdiv(G * DOUTC, B), B, 0, stream>>>(sums, cnt, out, G);
}